// Round 6
// baseline (391.005 us; speedup 1.0000x reference)
//
#include <hip/hip_runtime.h>
#include <hip/hip_bf16.h>
#include <string.h>

typedef _Float16 half8 __attribute__((ext_vector_type(8)));
typedef _Float16 half4 __attribute__((ext_vector_type(4)));
typedef float f32x4 __attribute__((ext_vector_type(4)));
typedef float f32x16 __attribute__((ext_vector_type(16)));

#define NTOK 4096
#define CDIM 256
#define LOG2E 1.44269504f

#define GLD_LDS16(g, l) __builtin_amdgcn_global_load_lds( \
    (const __attribute__((address_space(1))) void*)(g), \
    (__attribute__((address_space(3))) void*)(l), 16, 0, 0)

static __device__ __forceinline__ unsigned pk16(float a, float b) {
    auto h = __builtin_amdgcn_cvt_pkrtz(a, b);
    unsigned u;
    __builtin_memcpy(&u, &h, 4);
    return u;
}

// ===========================================================================
// PATH A kernels (needs ~84.4 MB workspace)
// ===========================================================================

// ---- cvtW: W fp32 -> Wh fp16 [proj][d][c]; Wq scaled by log2e -------------
__global__ __launch_bounds__(256) void cvtW_kernel(
    const float* __restrict__ Wq, const float* __restrict__ Wk,
    const float* __restrict__ Wv, _Float16* __restrict__ Wh)
{
    int pid = blockIdx.x * 256 + threadIdx.x;       // 96 blocks * 256 = 24576
    int base = pid * 8;                             // 196608 elems
    int proj = base >> 16;
    int within = base & 65535;
    const float* src = (proj == 0 ? Wq : (proj == 1 ? Wk : Wv)) + within;
    float sc = (proj == 0) ? LOG2E : 1.0f;
    float4 a = *(const float4*)(src);
    float4 b = *(const float4*)(src + 4);
    half8 h = { (_Float16)(a.x*sc), (_Float16)(a.y*sc), (_Float16)(a.z*sc), (_Float16)(a.w*sc),
                (_Float16)(b.x*sc), (_Float16)(b.y*sc), (_Float16)(b.z*sc), (_Float16)(b.w*sc) };
    *(half8*)(Wh + base) = h;
}

// ---- cvtX: x fp32 [b][c][n] -> Xt fp16 [bs][n][c] (token-major) -----------
__global__ __launch_bounds__(256) void cvtX_kernel(
    const float* __restrict__ x1, const float* __restrict__ x2,
    _Float16* __restrict__ Xt)
{
    __shared__ __align__(16) _Float16 Xl[64][264];
    const int t = threadIdx.x;
    const int bs = blockIdx.x >> 6;
    const int n0 = (blockIdx.x & 63) * 64;
    const int s = bs & 1, b = bs >> 1;
    const float* x = (s ? x2 : x1) + (size_t)b * CDIM * NTOK;
#pragma unroll
    for (int i = 0; i < 16; i++) {
        int id = t + 256 * i;
        int c = id >> 4, n4 = (id & 15) * 4;
        float4 v = *(const float4*)(x + (size_t)c * NTOK + n0 + n4);
        Xl[n4 + 0][c] = (_Float16)v.x;
        Xl[n4 + 1][c] = (_Float16)v.y;
        Xl[n4 + 2][c] = (_Float16)v.z;
        Xl[n4 + 3][c] = (_Float16)v.w;
    }
    __syncthreads();
    uint4* dst = (uint4*)(Xt + ((size_t)bs * NTOK + n0) * CDIM);
#pragma unroll
    for (int i = 0; i < 8; i++) {
        int id = t + 256 * i;
        int row = id >> 5, ck = id & 31;
        dst[(size_t)row * 32 + ck] = *(const uint4*)&Xl[row][ck * 8];
    }
}

// ---- proj2: fp16-staged projections -------------------------------------
// Q,K token-major [bs][N][C]; V channel-major [bs][C][N].
__global__ __launch_bounds__(256, 2) void proj2_kernel(
    const _Float16* __restrict__ Xt, const _Float16* __restrict__ Wh,
    const float* __restrict__ bq, const float* __restrict__ bk,
    const float* __restrict__ bv,
    _Float16* __restrict__ Qh, _Float16* __restrict__ Kh,
    _Float16* __restrict__ Vt)
{
    __shared__ __align__(16) _Float16 Xl[64][264];
    __shared__ __align__(16) _Float16 Wl[64][264];
    __shared__ __align__(16) _Float16 Ol[64][68];

    const int t = threadIdx.x;
    const int lane = t & 63;
    const int w = t >> 6;
    const int bs = blockIdx.x >> 6;
    const int n0 = (blockIdx.x & 63) * 64;

    // stage X tile once (fp16, no transpose needed)
    const uint4* xsrc = (const uint4*)(Xt + ((size_t)bs * NTOK + n0) * CDIM);
#pragma unroll
    for (int i = 0; i < 8; i++) {
        int id = t + 256 * i;
        int row = id >> 5, ck = id & 31;
        *(uint4*)&Xl[row][ck * 8] = xsrc[(size_t)row * 32 + ck];
    }

    for (int proj = 0; proj < 3; proj++) {
        const float* bp = proj == 0 ? bq : (proj == 1 ? bk : bv);
        const float bscale = (proj == 0) ? LOG2E : 1.0f;
        for (int dt = 0; dt < 4; dt++) {
            const int d0 = dt * 64;
            __syncthreads();
            const uint4* wsrc = (const uint4*)(Wh + ((size_t)proj * 256 + d0) * CDIM);
#pragma unroll
            for (int i = 0; i < 8; i++) {
                int id = t + 256 * i;
                int row = id >> 5, ck = id & 31;
                *(uint4*)&Wl[row][ck * 8] = wsrc[(size_t)row * 32 + ck];
            }
            __syncthreads();

            f32x4 acc[4];
            const f32x4 fz = {0.f, 0.f, 0.f, 0.f};
#pragma unroll
            for (int nt = 0; nt < 4; nt++) acc[nt] = fz;
#pragma unroll
            for (int cc = 0; cc < 8; cc++) {
                half8 wf = *(const half8*)&Wl[16 * w + (lane & 15)][cc * 32 + (lane >> 4) * 8];
#pragma unroll
                for (int nt = 0; nt < 4; nt++) {
                    half8 xf = *(const half8*)&Xl[nt * 16 + (lane & 15)][cc * 32 + (lane >> 4) * 8];
                    acc[nt] = __builtin_amdgcn_mfma_f32_16x16x32_f16(wf, xf, acc[nt], 0, 0, 0);
                }
            }
#pragma unroll
            for (int r = 0; r < 4; r++) {
                float bias = bp[d0 + 16 * w + (lane >> 4) * 4 + r] * bscale;
#pragma unroll
                for (int nt = 0; nt < 4; nt++) {
                    _Float16 hv = (_Float16)(acc[nt][r] + bias);
                    if (proj < 2) Ol[nt * 16 + (lane & 15)][16 * w + (lane >> 4) * 4 + r] = hv;
                    else          Ol[16 * w + (lane >> 4) * 4 + r][nt * 16 + (lane & 15)] = hv;
                }
            }
            __syncthreads();
            _Float16* dst;
            size_t stride;
            if (proj == 0)      { dst = Qh + ((size_t)bs * NTOK + n0) * CDIM + d0; stride = CDIM; }
            else if (proj == 1) { dst = Kh + ((size_t)bs * NTOK + n0) * CDIM + d0; stride = CDIM; }
            else                { dst = Vt + ((size_t)bs * CDIM + d0) * NTOK + n0; stride = NTOK; }
#pragma unroll
            for (int i = 0; i < 4; i++) {
                int id = t + 256 * i;
                int row = id >> 4, c4 = (id & 15) * 4;
                *(half4*)(dst + (size_t)row * stride + c4) = *(const half4*)&Ol[row][c4];
            }
        }
    }
}

// ---- flash_half: half the token range per block, no inter-half barrier ----
// grid 512 = bs(8, low bits: XCD-affine) x qt(32) x h(2); 256 thr, 4 waves.
// Wave w: q-rows qt*128 + w*32 ..+31.  KVBLK=32, dbuf LDS 64KB -> 2 blk/CU.
// Writes unnormalized Op fp16 [h][bs][c][n] + Ml {m,l} f32 [h][bs][n].
__global__ __launch_bounds__(256, 2) void flash_half(
    const _Float16* __restrict__ Qh, const _Float16* __restrict__ Kh,
    const _Float16* __restrict__ Vt, _Float16* __restrict__ Op,
    float* __restrict__ Ml)
{
    __shared__ __align__(16) char smem[65536];   // 2 x (K 16KB | V 16KB)

    const int t = threadIdx.x, lane = t & 63;
    const int w = t >> 6;                 // 0..3 (= qg)
    const int l5 = lane & 31, hi = lane >> 5;
    const int bid = blockIdx.x;
    const int bs = bid & 7;
    const int rest = bid >> 3;
    const int qt = rest & 31;
    const int h = rest >> 5;
    const int n0 = qt * 128;
    const int s = bs & 1, b = bs >> 1;
    const int tokbase = h * 2048;

    // Q B-frags (Q pre-scaled by log2e): col n = n0 + w*32 + l5
    half8 qf[16];
    {
        const _Float16* qp = Qh + ((size_t)bs * NTOK + n0 + w * 32 + l5) * CDIM + hi * 8;
#pragma unroll
        for (int cc = 0; cc < 16; cc++) qf[cc] = *(const half8*)(qp + cc * 16);
    }

    const int bsK = b * 2 + (s ^ 1);
    const uint4* const Ku = (const uint4*)(Kh + (size_t)bsK * NTOK * CDIM);
    const uint4* const Vu = (const uint4*)(Vt + (size_t)bs * CDIM * NTOK);

    float m_run = -1e30f, l_run = 0.f;
    f32x16 Oacc[8];
    const f32x16 FZ16 = {0,0,0,0,0,0,0,0,0,0,0,0,0,0,0,0};
#pragma unroll
    for (int ct = 0; ct < 8; ct++) Oacc[ct] = FZ16;

    // fragment-ordered staging: K frag cc at +cc*1024, V frag f=kc*8+ct at
    // +16384+f*1024; dest linear (base + lane*16), src per-lane permuted.
    auto stage = [&](int buf, int kt) {
        const int m0 = tokbase + kt * 32;
        char* base = smem + buf * 32768;
#pragma unroll
        for (int i = 0; i < 4; i++) {
            int cc = w * 4 + i;
            GLD_LDS16(Ku + (size_t)(m0 + l5) * 32 + cc * 2 + hi,
                      base + cc * 1024 + lane * 16);
        }
#pragma unroll
        for (int i = 0; i < 4; i++) {
            int f = w * 4 + i;
            int kc = f >> 3, ct = f & 7;
            GLD_LDS16(Vu + (size_t)(ct * 32 + l5) * 512 + (m0 >> 3) + kc * 2 + hi,
                      base + 16384 + f * 1024 + lane * 16);
        }
    };

    stage(0, 0);
    __syncthreads();

    for (int kt = 0; kt < 64; kt++) {
        const int cur = kt & 1;
        if (kt < 63) stage(cur ^ 1, kt + 1);
        const char* Kb = smem + cur * 32768;
        const char* Vb = Kb + 16384;

        // ---- S^T = K Q^T (2 independent 8-deep chains)
        f32x16 sfA = FZ16, sfB = FZ16;
        __builtin_amdgcn_s_setprio(1);
#pragma unroll
        for (int cc = 0; cc < 8; cc++) {
            half8 kfA = *(const half8*)(Kb + cc * 1024 + lane * 16);
            half8 kfB = *(const half8*)(Kb + (cc + 8) * 1024 + lane * 16);
            sfA = __builtin_amdgcn_mfma_f32_32x32x16_f16(kfA, qf[cc], sfA, 0, 0, 0);
            sfB = __builtin_amdgcn_mfma_f32_32x32x16_f16(kfB, qf[cc + 8], sfB, 0, 0, 0);
        }
        __builtin_amdgcn_s_setprio(0);
        f32x16 sf = sfA + sfB;

        // ---- online softmax in log2 domain (Q pre-scaled); row q = l5
        float pm = fmaxf(fmaxf(fmaxf(sf[0], sf[1]), fmaxf(sf[2], sf[3])),
                         fmaxf(fmaxf(sf[4], sf[5]), fmaxf(sf[6], sf[7])));
        float pm2 = fmaxf(fmaxf(fmaxf(sf[8], sf[9]), fmaxf(sf[10], sf[11])),
                          fmaxf(fmaxf(sf[12], sf[13]), fmaxf(sf[14], sf[15])));
        pm = fmaxf(pm, pm2);
        pm = fmaxf(pm, __shfl_xor(pm, 32));

        if (__any(pm > m_run + 11.54f)) {        // defer-max (log2 units)
            float nm = fmaxf(m_run, pm);
            float sc = exp2f(m_run - nm);
            m_run = nm;
            l_run *= sc;
#pragma unroll
            for (int reg = 0; reg < 16; reg++) {
                float sr = __shfl(sc, (reg & 3) + 8 * (reg >> 2) + 4 * hi);
#pragma unroll
                for (int ct = 0; ct < 8; ct++) Oacc[ct][reg] *= sr;
            }
        }

#pragma unroll
        for (int r = 0; r < 16; r++) sf[r] = exp2f(sf[r] - m_run);

        // ---- P -> A-frags: 8 cvt_pk + 4 permlane32_swap (proven direction)
        uint4 paw[2];
#pragma unroll
        for (int kc = 0; kc < 2; kc++) {
            const int qe = kc * 8;
            unsigned A01 = pk16(sf[qe + 0], sf[qe + 1]);
            unsigned A23 = pk16(sf[qe + 2], sf[qe + 3]);
            unsigned B01 = pk16(sf[qe + 4], sf[qe + 5]);
            unsigned B23 = pk16(sf[qe + 6], sf[qe + 7]);
            unsigned d0 = A01, s0 = B01;
            asm volatile("v_permlane32_swap_b32 %0, %1" : "+v"(d0), "+v"(s0));
            unsigned d1 = A23, s1 = B23;
            asm volatile("v_permlane32_swap_b32 %0, %1" : "+v"(d1), "+v"(s1));
            paw[kc].x = d0; paw[kc].y = d1; paw[kc].z = s0; paw[kc].w = s1;
        }

        // ---- O += P V
        __builtin_amdgcn_s_setprio(1);
#pragma unroll
        for (int kc = 0; kc < 2; kc++) {
            half8 pa;
            __builtin_memcpy(&pa, &paw[kc], 16);
#pragma unroll
            for (int ct = 0; ct < 8; ct++) {
                half8 vf = *(const half8*)(Vb + (kc * 8 + ct) * 1024 + lane * 16);
                Oacc[ct] = __builtin_amdgcn_mfma_f32_32x32x16_f16(pa, vf, Oacc[ct], 0, 0, 0);
            }
        }
        __builtin_amdgcn_s_setprio(0);

        // ---- l update (VALU, overlaps PV MFMAs)
        float lsum = ((sf[0] + sf[1]) + (sf[2] + sf[3])) + ((sf[4] + sf[5]) + (sf[6] + sf[7]))
                   + ((sf[8] + sf[9]) + (sf[10] + sf[11])) + ((sf[12] + sf[13]) + (sf[14] + sf[15]));
        lsum += __shfl_xor(lsum, 32);
        l_run += lsum;

        __syncthreads();
    }

    // ---- write Ml (per q-row; lanes hi==0)
    if (hi == 0) {
        float2 ml = make_float2(m_run, l_run);
        *(float2*)(Ml + ((size_t)(h * 8 + bs) * NTOK + n0 + w * 32 + l5) * 2) = ml;
    }

    // ---- epilogue: unnormalized O -> fp16, transpose via LDS, store [c][n]
    _Float16* const Olp = (_Float16*)smem;   // [128 c][136 n pad]
#pragma unroll
    for (int hcc = 0; hcc < 2; hcc++) {
        __syncthreads();
#pragma unroll
        for (int ct4 = 0; ct4 < 4; ct4++) {
            int ct = hcc * 4 + ct4;
            int cl = ct4 * 32 + l5;
#pragma unroll
            for (int reg = 0; reg < 16; reg++) {
                int n = w * 32 + (reg & 3) + 8 * (reg >> 2) + 4 * hi;
                Olp[cl * 136 + n] = (_Float16)Oacc[ct][reg];
            }
        }
        __syncthreads();
        _Float16* obase = Op + ((size_t)(h * 8 + bs) * CDIM + hcc * 128) * NTOK + n0;
#pragma unroll
        for (int i = 0; i < 8; i++) {
            int id = t + 256 * i;
            int c = id >> 4, ch = id & 15;
            *(uint4*)(obase + (size_t)c * NTOK + ch * 8) = *(const uint4*)&Olp[c * 136 + ch * 8];
        }
    }
}

// ---- merge: out[c][n] = w0(n) Op0[c][n] + w1(n) Op1[c][n] ----------------
__global__ __launch_bounds__(256) void merge_kernel(
    const _Float16* __restrict__ Op, const float* __restrict__ Ml,
    float* __restrict__ out)
{
    __shared__ float w0s[256], w1s[256];
    const int t = threadIdx.x;
    const int bid = blockIdx.x;               // 1024 = bs(8) x cb(8) x nb(16)
    const int bs = bid & 7;
    const int cb = (bid >> 3) & 7;
    const int nb = bid >> 6;
    const int s = bs & 1, b = bs >> 1;

    {
        int n = nb * 256 + t;
        float2 ml0 = *(const float2*)(Ml + ((size_t)(0 + bs) * NTOK + n) * 2);
        float2 ml1 = *(const float2*)(Ml + ((size_t)(8 + bs) * NTOK + n) * 2);
        float mstar = fmaxf(ml0.x, ml1.x);
        float e0 = exp2f(ml0.x - mstar), e1 = exp2f(ml1.x - mstar);
        float inv = 1.0f / (e0 * ml0.y + e1 * ml1.y);
        w0s[t] = e0 * inv;
        w1s[t] = e1 * inv;
    }
    __syncthreads();

    const size_t cbase0 = ((size_t)(0 + bs) * CDIM + cb * 32) * NTOK + nb * 256;
    const size_t cbase1 = ((size_t)(8 + bs) * CDIM + cb * 32) * NTOK + nb * 256;
    float* obase = out + ((size_t)(s * 4 + b) * CDIM + cb * 32) * NTOK + nb * 256;
#pragma unroll
    for (int i = 0; i < 4; i++) {
        int id = t + 256 * i;
        int c = id >> 5, nc = (id & 31) * 8;
        half8 a = *(const half8*)(Op + cbase0 + (size_t)c * NTOK + nc);
        half8 d = *(const half8*)(Op + cbase1 + (size_t)c * NTOK + nc);
        float4 o0, o1;
        float* op = &o0.x;
#pragma unroll
        for (int j = 0; j < 8; j++) {
            float v = w0s[nc + j] * (float)a[j] + w1s[nc + j] * (float)d[j];
            if (j < 4) (&o0.x)[j] = v; else (&o1.x)[j - 4] = v;
        }
        (void)op;
        *(float4*)(obase + (size_t)c * NTOK + nc) = o0;
        *(float4*)(obase + (size_t)c * NTOK + nc + 4) = o1;
    }
}

// ===========================================================================
// PATH C kernels (r5 fallback, known-good, 48 MB ws)
// ===========================================================================
__global__ __launch_bounds__(256, 2) void proj_kernel(
    const float* __restrict__ x1, const float* __restrict__ x2,
    const float* __restrict__ Wq, const float* __restrict__ bq,
    const float* __restrict__ Wk, const float* __restrict__ bk,
    const float* __restrict__ Wv, const float* __restrict__ bv,
    _Float16* __restrict__ Qh, _Float16* __restrict__ Kh,
    _Float16* __restrict__ Vt)
{
    __shared__ __align__(16) _Float16 Xl[64][264];
    __shared__ __align__(16) _Float16 Wl[64][264];
    __shared__ __align__(16) _Float16 Ol[64][68];

    const int t = threadIdx.x;
    const int lane = t & 63;
    const int w = t >> 6;
    const int bs = blockIdx.x >> 6;
    const int n0 = (blockIdx.x & 63) * 64;
    const int s = bs & 1, b = bs >> 1;
    const float* x = (s ? x2 : x1) + (size_t)b * CDIM * NTOK;

#pragma unroll
    for (int i = 0; i < 16; i++) {
        int id = t + 256 * i;
        int c = id >> 4, n4 = (id & 15) * 4;
        float4 v = *(const float4*)(x + (size_t)c * NTOK + n0 + n4);
        Xl[n4 + 0][c] = (_Float16)v.x;
        Xl[n4 + 1][c] = (_Float16)v.y;
        Xl[n4 + 2][c] = (_Float16)v.z;
        Xl[n4 + 3][c] = (_Float16)v.w;
    }
    for (int proj = 0; proj < 3; proj++) {
        const float* Wp = proj == 0 ? Wq : (proj == 1 ? Wk : Wv);
        const float* bp = proj == 0 ? bq : (proj == 1 ? bk : bv);
        for (int dt = 0; dt < 4; dt++) {
            const int d0 = dt * 64;
            __syncthreads();
#pragma unroll
            for (int i = 0; i < 16; i++) {
                int id = t + 256 * i;
                int d = id >> 6, c4 = (id & 63) * 4;
                float4 v = *(const float4*)(Wp + (size_t)(d0 + d) * CDIM + c4);
                half4 hh = { (_Float16)v.x, (_Float16)v.y, (_Float16)v.z, (_Float16)v.w };
                *(half4*)&Wl[d][c4] = hh;
            }
            __syncthreads();
            f32x4 acc[4];
            const f32x4 fz = {0.f, 0.f, 0.f, 0.f};
#pragma unroll
            for (int nt = 0; nt < 4; nt++) acc[nt] = fz;
#pragma unroll
            for (int cc = 0; cc < 8; cc++) {
                half8 wf = *(const half8*)&Wl[16 * w + (lane & 15)][cc * 32 + (lane >> 4) * 8];
#pragma unroll
                for (int nt = 0; nt < 4; nt++) {
                    half8 xf = *(const half8*)&Xl[nt * 16 + (lane & 15)][cc * 32 + (lane >> 4) * 8];
                    acc[nt] = __builtin_amdgcn_mfma_f32_16x16x32_f16(wf, xf, acc[nt], 0, 0, 0);
                }
            }
#pragma unroll
            for (int r = 0; r < 4; r++) {
                float bias = bp[d0 + 16 * w + (lane >> 4) * 4 + r];
#pragma unroll
                for (int nt = 0; nt < 4; nt++) {
                    _Float16 hv = (_Float16)(acc[nt][r] + bias);
                    if (proj < 2) Ol[nt * 16 + (lane & 15)][16 * w + (lane >> 4) * 4 + r] = hv;
                    else          Ol[16 * w + (lane >> 4) * 4 + r][nt * 16 + (lane & 15)] = hv;
                }
            }
            __syncthreads();
            _Float16* dst;
            size_t stride;
            if (proj == 0)      { dst = Qh + ((size_t)bs * NTOK + n0) * CDIM + d0; stride = CDIM; }
            else if (proj == 1) { dst = Kh + ((size_t)bs * NTOK + n0) * CDIM + d0; stride = CDIM; }
            else                { dst = Vt + ((size_t)bs * CDIM + d0) * NTOK + n0; stride = NTOK; }
#pragma unroll
            for (int i = 0; i < 4; i++) {
                int id = t + 256 * i;
                int row = id >> 4, c4 = (id & 15) * 4;
                *(half4*)(dst + (size_t)row * stride + c4) = *(const half4*)&Ol[row][c4];
            }
        }
    }
}

__global__ __launch_bounds__(512, 2) void flash_kernel(
    const _Float16* __restrict__ Qh, const _Float16* __restrict__ Kh,
    const _Float16* __restrict__ Vt, float* __restrict__ out)
{
    __shared__ __align__(16) char smem[131072];
    const int t = threadIdx.x, lane = t & 63;
    const int w = t >> 6;
    const int qg = w >> 1, mg = w & 1;
    const int l5 = lane & 31, hi = lane >> 5;
    const int bs = blockIdx.x & 7;
    const int qt = blockIdx.x >> 3;
    const int n0 = qt * 128;
    const int s = bs & 1, b = bs >> 1;

    half8 qf[16];
    {
        const _Float16* qp = Qh + ((size_t)bs * NTOK + n0 + qg * 32 + l5) * CDIM + hi * 8;
#pragma unroll
        for (int cc = 0; cc < 16; cc++) qf[cc] = *(const half8*)(qp + cc * 16);
    }
    const int bsK = b * 2 + (s ^ 1);
    const uint4* const Ksrc = (const uint4*)(Kh + (size_t)bsK * NTOK * CDIM);
    const uint4* const Vsrc = (const uint4*)(Vt + (size_t)bs * CDIM * NTOK);

    float m_run = -1e30f, l_run = 0.f;
    f32x16 Oacc[8];
    const f32x16 FZ16 = {0,0,0,0,0,0,0,0,0,0,0,0,0,0,0,0};
#pragma unroll
    for (int ct = 0; ct < 8; ct++) Oacc[ct] = FZ16;

    auto stage = [&](int buf, int kt) {
        const int m0 = kt * 64;
        char* base = smem + buf * 65536;
        if (w < 4) {
#pragma unroll
            for (int i = 0; i < 8; i++) {
                int instr = w * 8 + i;
                int cc = instr >> 1, mt = instr & 1;
                GLD_LDS16(Ksrc + (size_t)(m0 + mt * 32 + l5) * 32 + cc * 2 + hi,
                          base + (instr * 64) * 16 + (hi * 32 + l5) * 16);
            }
        } else {
#pragma unroll
            for (int i = 0; i < 8; i++) {
                int instr = (w - 4) * 8 + i;
                int kcg = instr >> 3, ct = instr & 7;
                GLD_LDS16(Vsrc + (size_t)(ct * 32 + l5) * 512 + (m0 >> 3) + kcg * 2 + hi,
                          base + 32768 + (instr * 64) * 16 + (hi * 32 + l5) * 16);
            }
        }
    };

    stage(0, 0);
    __syncthreads();

    for (int kt = 0; kt < 64; kt++) {
        const int cur = kt & 1;
        if (kt < 63) stage(cur ^ 1, kt + 1);
        const char* Kb = smem + cur * 65536;
        const char* Vbuf = Kb + 32768;

        f32x16 sf = FZ16;
#pragma unroll
        for (int cc = 0; cc < 16; cc++) {
            half8 kf = *(const half8*)(Kb + (cc * 2 + mg) * 1024 + hi * 512 + l5 * 16);
            sf = __builtin_amdgcn_mfma_f32_32x32x16_f16(kf, qf[cc], sf, 0, 0, 0);
        }
        float pm = sf[0];
#pragma unroll
        for (int r = 1; r < 16; r++) pm = fmaxf(pm, sf[r]);
        pm = fmaxf(pm, __shfl_xor(pm, 32));
        if (__any(pm > m_run + 8.0f)) {
            float nm = fmaxf(m_run, pm);
            float sc = __expf(m_run - nm);
            m_run = nm;
            l_run *= sc;
#pragma unroll
            for (int reg = 0; reg < 16; reg++) {
                float sr = __shfl(sc, (reg & 3) + 8 * (reg >> 2) + 4 * hi);
#pragma unroll
                for (int ct = 0; ct < 8; ct++) Oacc[ct][reg] *= sr;
            }
        }
        float lsum = 0.f;
#pragma unroll
        for (int r = 0; r < 16; r++) {
            float p = __expf(sf[r] - m_run);
            sf[r] = p;
            lsum += p;
        }
        lsum += __shfl_xor(lsum, 32);
        l_run += lsum;

        uint4 paw[2];
#pragma unroll
        for (int kc = 0; kc < 2; kc++) {
            const int qe = kc * 8;
            unsigned A01 = pk16(sf[qe + 0], sf[qe + 1]);
            unsigned A23 = pk16(sf[qe + 2], sf[qe + 3]);
            unsigned B01 = pk16(sf[qe + 4], sf[qe + 5]);
            unsigned B23 = pk16(sf[qe + 6], sf[qe + 7]);
            unsigned d0 = A01, s0 = B01;
            asm volatile("v_permlane32_swap_b32 %0, %1" : "+v"(d0), "+v"(s0));
            unsigned d1 = A23, s1 = B23;
            asm volatile("v_permlane32_swap_b32 %0, %1" : "+v"(d1), "+v"(s1));
            paw[kc].x = d0; paw[kc].y = d1; paw[kc].z = s0; paw[kc].w = s1;
        }
#pragma unroll
        for (int kc = 0; kc < 2; kc++) {
            half8 pa;
            __builtin_memcpy(&pa, &paw[kc], 16);
            const int kcg = mg * 2 + kc;
#pragma unroll
            for (int ct = 0; ct < 8; ct++) {
                half8 vf = *(const half8*)(Vbuf + ((kcg * 8 + ct) * 64) * 16 + (hi * 32 + l5) * 16);
                Oacc[ct] = __builtin_amdgcn_mfma_f32_32x32x16_f16(pa, vf, Oacc[ct], 0, 0, 0);
            }
        }
        __syncthreads();
    }

    float* const mlbuf = (float*)(smem + 65536);
    if (mg == 1 && hi == 0) {
        *(float2*)(mlbuf + (qg * 32 + l5) * 2) = make_float2(m_run, l_run);
    }
    if (mg == 1) {
#pragma unroll
        for (int ct = 0; ct < 4; ct++)
#pragma unroll
            for (int rc = 0; rc < 4; rc++) {
                f32x4 v = { Oacc[ct][rc*4+0], Oacc[ct][rc*4+1], Oacc[ct][rc*4+2], Oacc[ct][rc*4+3] };
                *(f32x4*)(smem + ((qg * 4 + ct) * 4 + rc) * 1024 + lane * 16) = v;
            }
    }
    __syncthreads();
    float a_s = 0.f, b_s = 0.f;
    if (mg == 0) {
        float2 ml = *(const float2*)(mlbuf + (qg * 32 + l5) * 2);
        float mstar = fmaxf(m_run, ml.x);
        float e0 = __expf(m_run - mstar), e1 = __expf(ml.x - mstar);
        float ltot = l_run * e0 + ml.y * e1;
        a_s = e0 / ltot; b_s = e1 / ltot;
#pragma unroll
        for (int ct = 0; ct < 4; ct++)
#pragma unroll
            for (int rc = 0; rc < 4; rc++) {
                f32x4 o1 = *(const f32x4*)(smem + ((qg * 4 + ct) * 4 + rc) * 1024 + lane * 16);
#pragma unroll
                for (int j = 0; j < 4; j++) {
                    int r = j + 8 * rc + 4 * hi;
                    Oacc[ct][rc*4+j] = Oacc[ct][rc*4+j] * __shfl(a_s, r) + o1[j] * __shfl(b_s, r);
                }
            }
    }
    __syncthreads();
    if (mg == 1) {
#pragma unroll
        for (int ct = 0; ct < 4; ct++)
#pragma unroll
            for (int rc = 0; rc < 4; rc++) {
                f32x4 v = { Oacc[ct+4][rc*4+0], Oacc[ct+4][rc*4+1], Oacc[ct+4][rc*4+2], Oacc[ct+4][rc*4+3] };
                *(f32x4*)(smem + ((qg * 4 + ct) * 4 + rc) * 1024 + lane * 16) = v;
            }
    }
    __syncthreads();
    if (mg == 0) {
#pragma unroll
        for (int ct = 0; ct < 4; ct++)
#pragma unroll
            for (int rc = 0; rc < 4; rc++) {
                f32x4 o1 = *(const f32x4*)(smem + ((qg * 4 + ct) * 4 + rc) * 1024 + lane * 16);
#pragma unroll
                for (int j = 0; j < 4; j++) {
                    int r = j + 8 * rc + 4 * hi;
                    Oacc[ct+4][rc*4+j] = Oacc[ct+4][rc*4+j] * __shfl(a_s, r) + o1[j] * __shfl(b_s, r);
                }
            }
    }
    float* obase = out + (size_t)(s * 4 + b) * CDIM * NTOK + n0;
    char* const Olp = smem;
#pragma unroll
    for (int hh = 0; hh < 2; hh++) {
        __syncthreads();
        if (mg == 0) {
#pragma unroll
            for (int ct4 = 0; ct4 < 4; ct4++) {
                int ct = hh * 4 + ct4;
                int cl = ct4 * 32 + l5;
#pragma unroll
                for (int reg = 0; reg < 16; reg++) {
                    int n = qg * 32 + (reg & 3) + 8 * (reg >> 2) + 4 * hi;
                    int byteoff = cl * 512 + n * 4;
                    *(float*)(Olp + (byteoff ^ ((cl & 7) << 4))) = Oacc[ct][reg];
                }
            }
        }
        __syncthreads();
#pragma unroll
        for (int i = 0; i < 8; i++) {
            int id = t + 512 * i;
            int c = id >> 5, nc = id & 31;
            f32x4 v = *(const f32x4*)(Olp + c * 512 + ((nc ^ (c & 7)) << 4));
            *(f32x4*)(obase + (size_t)(hh * 128 + c) * NTOK + nc * 4) = v;
        }
    }
}

// ===========================================================================
extern "C" void kernel_launch(void* const* d_in, const int* in_sizes, int n_in,
                              void* d_out, int out_size, void* d_ws, size_t ws_size,
                              hipStream_t stream) {
    const float* x1 = (const float*)d_in[0];
    const float* x2 = (const float*)d_in[1];
    const float* Wq = (const float*)d_in[2];
    const float* bq = (const float*)d_in[3];
    const float* Wk = (const float*)d_in[4];
    const float* bk = (const float*)d_in[5];
    const float* Wv = (const float*)d_in[6];
    const float* bv = (const float*)d_in[7];

    const size_t QKV_HALFS = (size_t)8 * NTOK * CDIM;      // per tensor
    _Float16* Qh = (_Float16*)d_ws;
    _Float16* Kh = Qh + QKV_HALFS;
    _Float16* Vt = Kh + QKV_HALFS;

    const size_t NEED_A = 3 * QKV_HALFS * 2                // QKV 48 MB
                        + 2 * QKV_HALFS * 2                // Op 32 MB
                        + (size_t)2 * 8 * NTOK * 2 * 4;    // Ml 0.5 MB

    if (ws_size >= NEED_A) {
        // PATH A
        _Float16* Xt = Vt + QKV_HALFS;                     // overlaid with Op
        _Float16* Op = Vt + QKV_HALFS;
        float* Ml = (float*)(Op + 2 * QKV_HALFS);
        _Float16* Wh = (_Float16*)(Ml + (size_t)2 * 8 * NTOK * 2);  // wait: Ml sized above
        // place Wh safely right after Ml
        cvtW_kernel<<<dim3(96), dim3(256), 0, stream>>>(Wq, Wk, Wv, Wh);
        cvtX_kernel<<<dim3(512), dim3(256), 0, stream>>>(x1, x2, Xt);
        proj2_kernel<<<dim3(512), dim3(256), 0, stream>>>(Xt, Wh, bq, bk, bv, Qh, Kh, Vt);
        flash_half<<<dim3(512), dim3(256), 0, stream>>>(Qh, Kh, Vt, Op, Ml);
        merge_kernel<<<dim3(1024), dim3(256), 0, stream>>>(Op, Ml, (float*)d_out);
    } else {
        // PATH C (r5 fallback)
        proj_kernel<<<dim3(512), dim3(256), 0, stream>>>(x1, x2, Wq, bq, Wk, bk, Wv, bv, Qh, Kh, Vt);
        flash_kernel<<<dim3(256), dim3(512), 0, stream>>>(Qh, Kh, Vt, (float*)d_out);
    }
}